// Round 2
// baseline (2106.497 us; speedup 1.0000x reference)
//
#include <hip/hip_runtime.h>
#include <math.h>

// ---------------------------------------------------------------------------
// SplineConv GNN: 3 layers (in=2->16, 16->16, 16->16), K=5 per dim (dim=2),
// degree-1 open B-spline, mean aggregation, root weight + bias, ReLU.
// Final: FC [16,1] + bias + sigmoid -> out[N] f32.
//
// Round 2: edge kernel restructured for LDS throughput (was the bottleneck:
// 25.6M scalar ds_read_b32 + 4.8e7 conflict cycles per dispatch).
//  - W staged in LDS as bf16 (halves bytes; glorot weights ~0.2% rel err)
//  - one thread per (edge, o-half): 8 outputs/thread, ds_read_b128 per (tap,i)
//  - odd granule stride per kernel index spreads banks by wi
// ---------------------------------------------------------------------------

#define KS 5

#define BF2F_LO(u) __uint_as_float((u) << 16)
#define BF2F_HI(u) __uint_as_float((u) & 0xffff0000u)

// ---- degree count -----------------------------------------------------------
__global__ void deg_count_kernel(const int* __restrict__ dst, float* __restrict__ deg, int E) {
    int stride = gridDim.x * blockDim.x;
    for (int e = blockIdx.x * blockDim.x + threadIdx.x; e < E; e += stride) {
        atomicAdd(&deg[dst[e]], 1.0f);
    }
}

__global__ void deg_inv_kernel(float* __restrict__ deg, int N) {
    int i = blockIdx.x * blockDim.x + threadIdx.x;
    if (i < N) deg[i] = 1.0f / fmaxf(deg[i], 1.0f);
}

// ---- edge message + scatter-add --------------------------------------------
// One thread per (edge, o-half). 2 threads per edge, 8 outputs each.
// LDS layout: granule(16B) index g(k,i,hf) = k*(2*IN+1) + 2*i + hf, holding
// bf16 weights W[k][i][hf*8 .. hf*8+7]. Odd stride (2*IN+1) => granule column
// (g mod 8) = (k + 2i + hf) mod 8, randomized across edges by k.
template <int IN>
__global__ __launch_bounds__(256) void edge_kernel(
        const float* __restrict__ h,     // [N, IN]
        const int* __restrict__ src,
        const int* __restrict__ dst,
        const float* __restrict__ eattr, // [E, 2]
        const float* __restrict__ W,     // [25, IN, 16] f32
        float* __restrict__ agg,         // [N, 16] (zeroed)
        int E) {
    constexpr int GSTRIDE = 2 * IN + 1;
    __shared__ ushort Wl[25 * GSTRIDE * 8];

    for (int idx = threadIdx.x; idx < 25 * IN * 16; idx += blockDim.x) {
        int k = idx / (IN * 16);
        int r = idx - k * IN * 16;
        int i = r >> 4;
        int o = r & 15;
        unsigned u = __float_as_uint(W[idx]);
        unsigned bf = (u + 0x7fffu + ((u >> 16) & 1u)) >> 16;  // RNE to bf16
        Wl[(k * GSTRIDE + 2 * i + (o >> 3)) * 8 + (o & 7)] = (ushort)bf;
    }
    __syncthreads();

    int t = blockIdx.x * blockDim.x + threadIdx.x;
    int e = t >> 1;
    if (e >= E) return;
    int hf = t & 1;

    float2 ea = reinterpret_cast<const float2*>(eattr)[e];
    float a0 = ea.x * (float)(KS - 1);
    float a1 = ea.y * (float)(KS - 1);
    float k0 = fminf(fmaxf(floorf(a0), 0.0f), (float)(KS - 2));
    float k1 = fminf(fmaxf(floorf(a1), 0.0f), (float)(KS - 2));
    float f0 = a0 - k0;
    float f1 = a1 - k1;
    int i0 = (int)k0;
    int i1 = (int)k1;
    float b0[2] = {1.0f - f0, f0};
    float b1[2] = {1.0f - f1, f1};

    int s = src[e];
    float hv[IN];
    if (IN == 16) {
        const float4* h4 = reinterpret_cast<const float4*>(h + (size_t)s * IN);
        #pragma unroll
        for (int q = 0; q < IN / 4; ++q) {
            float4 v = h4[q];
            hv[4 * q + 0] = v.x; hv[4 * q + 1] = v.y;
            hv[4 * q + 2] = v.z; hv[4 * q + 3] = v.w;
        }
    } else {
        const float2* h2 = reinterpret_cast<const float2*>(h + (size_t)s * IN);
        #pragma unroll
        for (int q = 0; q < IN / 2; ++q) {
            float2 v = h2[q];
            hv[2 * q + 0] = v.x; hv[2 * q + 1] = v.y;
        }
    }

    float acc[8];
    #pragma unroll
    for (int j = 0; j < 8; ++j) acc[j] = 0.0f;

    #pragma unroll
    for (int s1 = 0; s1 < 2; ++s1) {
        #pragma unroll
        for (int s0 = 0; s0 < 2; ++s0) {
            float bb = b0[s0] * b1[s1];
            int wi = (i0 + s0) + KS * (i1 + s1);
            int gbase = wi * GSTRIDE + hf;
            float p[8];
            #pragma unroll
            for (int j = 0; j < 8; ++j) p[j] = 0.0f;
            #pragma unroll
            for (int i = 0; i < IN; ++i) {
                uint4 wv = *reinterpret_cast<const uint4*>(&Wl[(gbase + 2 * i) * 8]);
                float hvi = hv[i];
                p[0] += hvi * BF2F_LO(wv.x); p[1] += hvi * BF2F_HI(wv.x);
                p[2] += hvi * BF2F_LO(wv.y); p[3] += hvi * BF2F_HI(wv.y);
                p[4] += hvi * BF2F_LO(wv.z); p[5] += hvi * BF2F_HI(wv.z);
                p[6] += hvi * BF2F_LO(wv.w); p[7] += hvi * BF2F_HI(wv.w);
            }
            #pragma unroll
            for (int j = 0; j < 8; ++j) acc[j] += bb * p[j];
        }
    }

    float* ap = &agg[(size_t)dst[e] * 16 + hf * 8];
    #pragma unroll
    for (int j = 0; j < 8; ++j) atomicAdd(&ap[j], acc[j]);
}

// ---- finalize: out = relu(agg * invdeg + hin @ root + bias) ----------------
template <int IN>
__global__ void finalize_kernel(const float* __restrict__ hin,    // [N, IN]
                                const float* __restrict__ root,   // [IN, 16]
                                const float* __restrict__ bias,   // [16]
                                const float* __restrict__ invdeg, // [N]
                                float* __restrict__ h,            // [N,16] in: agg / out: act
                                int N) {
    int t = blockIdx.x * blockDim.x + threadIdx.x;
    if (t >= N * 16) return;
    int o = t & 15;
    int n = t >> 4;
    float acc = h[t] * invdeg[n];
    #pragma unroll
    for (int i = 0; i < IN; ++i) acc += hin[(size_t)n * IN + i] * root[i * 16 + o];
    acc += bias[o];
    h[t] = fmaxf(acc, 0.0f);
}

// ---- final FC + sigmoid ----------------------------------------------------
__global__ void fc_kernel(const float* __restrict__ h,   // [N,16]
                          const float* __restrict__ fcw, // [16]
                          const float* __restrict__ fcb, // [1]
                          float* __restrict__ out, int N) {
    int n = blockIdx.x * blockDim.x + threadIdx.x;
    if (n >= N) return;
    const float4* h4 = reinterpret_cast<const float4*>(h + (size_t)n * 16);
    float acc = fcb[0];
    #pragma unroll
    for (int q = 0; q < 4; ++q) {
        float4 v = h4[q];
        acc += v.x * fcw[4 * q + 0] + v.y * fcw[4 * q + 1] +
               v.z * fcw[4 * q + 2] + v.w * fcw[4 * q + 3];
    }
    out[n] = 1.0f / (1.0f + expf(-acc));
}

extern "C" void kernel_launch(void* const* d_in, const int* in_sizes, int n_in,
                              void* d_out, int out_size, void* d_ws, size_t ws_size,
                              hipStream_t stream) {
    const float* x      = (const float*)d_in[0];   // [N,2]
    const int*   eidx   = (const int*)d_in[1];     // [2,E]
    const float* eattr  = (const float*)d_in[2];   // [E,2]
    const float* W1     = (const float*)d_in[3];
    const float* root1  = (const float*)d_in[4];
    const float* b1     = (const float*)d_in[5];
    const float* W2     = (const float*)d_in[6];
    const float* root2  = (const float*)d_in[7];
    const float* b2     = (const float*)d_in[8];
    const float* W3     = (const float*)d_in[9];
    const float* root3  = (const float*)d_in[10];
    const float* b3     = (const float*)d_in[11];
    const float* fcw    = (const float*)d_in[12];
    const float* fcb    = (const float*)d_in[13];
    float* out = (float*)d_out;

    const int N = in_sizes[0] / 2;
    const int E = in_sizes[2] / 2;
    const int* src = eidx;
    const int* dst = eidx + E;

    float* hA  = (float*)d_ws;            // [N,16]
    float* hB  = hA + (size_t)N * 16;     // [N,16]
    float* deg = hB + (size_t)N * 16;     // [N]

    const int BT = 256;
    const int edge_grid = (E * 2 + BT - 1) / BT;   // 2 threads per edge
    const int node_grid = (N * 16 + BT - 1) / BT;

    // degree (shared by all layers)
    hipMemsetAsync(deg, 0, (size_t)N * sizeof(float), stream);
    deg_count_kernel<<<2048, BT, 0, stream>>>(dst, deg, E);
    deg_inv_kernel<<<(N + BT - 1) / BT, BT, 0, stream>>>(deg, N);

    // layer 1: x[N,2] -> hA
    hipMemsetAsync(hA, 0, (size_t)N * 16 * sizeof(float), stream);
    edge_kernel<2><<<edge_grid, BT, 0, stream>>>(x, src, dst, eattr, W1, hA, E);
    finalize_kernel<2><<<node_grid, BT, 0, stream>>>(x, root1, b1, deg, hA, N);

    // layer 2: hA -> hB
    hipMemsetAsync(hB, 0, (size_t)N * 16 * sizeof(float), stream);
    edge_kernel<16><<<edge_grid, BT, 0, stream>>>(hA, src, dst, eattr, W2, hB, E);
    finalize_kernel<16><<<node_grid, BT, 0, stream>>>(hA, root2, b2, deg, hB, N);

    // layer 3: hB -> hA
    hipMemsetAsync(hA, 0, (size_t)N * 16 * sizeof(float), stream);
    edge_kernel<16><<<edge_grid, BT, 0, stream>>>(hB, src, dst, eattr, W3, hA, E);
    finalize_kernel<16><<<node_grid, BT, 0, stream>>>(hB, root3, b3, deg, hA, N);

    // final FC + sigmoid
    fc_kernel<<<(N + BT - 1) / BT, BT, 0, stream>>>(hA, fcw, fcb, out, N);
}

// Round 3
// 444.900 us; speedup vs baseline: 4.7348x; 4.7348x over previous
//
#include <hip/hip_runtime.h>
#include <hip/hip_fp16.h>
#include <math.h>

// ---------------------------------------------------------------------------
// SplineConv GNN: 3 layers (in=2->16, 16->16, 16->16), K=5 per dim (dim=2),
// degree-1 open B-spline, mean aggregation, root weight + bias, ReLU.
// Final: FC [16,1] + bias + sigmoid -> out[N] f32.
//
// Round 3:
//  - KEEP round-1 atomic mapping (16 threads/edge, channel-contiguous lanes:
//    one coalesced 64B line per edge per atomic instr; round-2's 8-atomic
//    split caused 8x write amplification, 100->800 MB).
//  - LDS fixed instead: transposed f32 layout Wl[k][o][i], row padded to 20
//    floats (o*5 mod 8 spreads all bank columns, rows 16B aligned) ->
//    4x ds_read_b128 per tap instead of 16x ds_read_b32.
//  - Basis/wi/src packed ONCE per edge (shared by all 3 layers) into uint4.
//  - Grid-stride so LDS staging runs per resident block, not per tile.
// ---------------------------------------------------------------------------

#define KS 5

// ---- degree count -----------------------------------------------------------
__global__ void deg_count_kernel(const int* __restrict__ dst, float* __restrict__ deg, int E) {
    int stride = gridDim.x * blockDim.x;
    for (int e = blockIdx.x * blockDim.x + threadIdx.x; e < E; e += stride) {
        atomicAdd(&deg[dst[e]], 1.0f);
    }
}

__global__ void deg_inv_kernel(float* __restrict__ deg, int N) {
    int i = blockIdx.x * blockDim.x + threadIdx.x;
    if (i < N) deg[i] = 1.0f / fmaxf(deg[i], 1.0f);
}

// ---- per-edge basis precompute ---------------------------------------------
// pack = { wi0|wi1<<8|wi2<<16|wi3<<24, f16(b0)|f16(b1)<<16, f16(b2)|f16(b3)<<16, src }
__global__ void pack_kernel(const float* __restrict__ eattr, const int* __restrict__ src,
                            uint4* __restrict__ pack, int E) {
    int stride = gridDim.x * blockDim.x;
    for (int e = blockIdx.x * blockDim.x + threadIdx.x; e < E; e += stride) {
        float2 ea = reinterpret_cast<const float2*>(eattr)[e];
        float a0 = ea.x * (float)(KS - 1);
        float a1 = ea.y * (float)(KS - 1);
        float k0 = fminf(fmaxf(floorf(a0), 0.0f), (float)(KS - 2));
        float k1 = fminf(fmaxf(floorf(a1), 0.0f), (float)(KS - 2));
        float f0 = a0 - k0, f1 = a1 - k1;
        int i0 = (int)k0, i1 = (int)k1;
        int w00 = i0 + KS * i1;
        unsigned wis = (unsigned)w00 | ((unsigned)(w00 + 1) << 8) |
                       ((unsigned)(w00 + KS) << 16) | ((unsigned)(w00 + KS + 1) << 24);
        float b00 = (1.0f - f0) * (1.0f - f1);
        float b10 = f0 * (1.0f - f1);
        float b01 = (1.0f - f0) * f1;
        float b11 = f0 * f1;
        unsigned y = (unsigned)__half_as_ushort(__float2half_rn(b00)) |
                     ((unsigned)__half_as_ushort(__float2half_rn(b10)) << 16);
        unsigned z = (unsigned)__half_as_ushort(__float2half_rn(b01)) |
                     ((unsigned)__half_as_ushort(__float2half_rn(b11)) << 16);
        pack[e] = make_uint4(wis, y, z, (unsigned)src[e]);
    }
}

__device__ __forceinline__ void decode_or_compute(
        bool haspack, const uint4* pack, const float* eattr, const int* srcp,
        int e, int& s, float b[4], int wi[4]) {
    if (haspack) {
        uint4 pk = pack[e];
        s = (int)pk.w;
        wi[0] = (int)(pk.x & 255); wi[1] = (int)((pk.x >> 8) & 255);
        wi[2] = (int)((pk.x >> 16) & 255); wi[3] = (int)(pk.x >> 24);
        b[0] = __half2float(__ushort_as_half((unsigned short)(pk.y & 0xffff)));
        b[1] = __half2float(__ushort_as_half((unsigned short)(pk.y >> 16)));
        b[2] = __half2float(__ushort_as_half((unsigned short)(pk.z & 0xffff)));
        b[3] = __half2float(__ushort_as_half((unsigned short)(pk.z >> 16)));
    } else {
        float2 ea = reinterpret_cast<const float2*>(eattr)[e];
        float a0 = ea.x * (float)(KS - 1);
        float a1 = ea.y * (float)(KS - 1);
        float k0 = fminf(fmaxf(floorf(a0), 0.0f), (float)(KS - 2));
        float k1 = fminf(fmaxf(floorf(a1), 0.0f), (float)(KS - 2));
        float f0 = a0 - k0, f1 = a1 - k1;
        int i0 = (int)k0, i1 = (int)k1;
        int w00 = i0 + KS * i1;
        wi[0] = w00; wi[1] = w00 + 1; wi[2] = w00 + KS; wi[3] = w00 + KS + 1;
        b[0] = (1.0f - f0) * (1.0f - f1);
        b[1] = f0 * (1.0f - f1);
        b[2] = (1.0f - f0) * f1;
        b[3] = f0 * f1;
        s = srcp[e];
    }
}

// ---- edge kernels -----------------------------------------------------------
// 16 threads per edge, o = t & 15. Grid-stride.
template <bool HASPACK>
__global__ __launch_bounds__(256) void edge16_kernel(
        const float* __restrict__ h,      // [N,16]
        const int* __restrict__ dst,
        const uint4* __restrict__ pack,   // [E] (if HASPACK)
        const float* __restrict__ eattr,  // [E,2] (if !HASPACK)
        const int* __restrict__ srcp,     // [E]   (if !HASPACK)
        const float* __restrict__ W,      // [25,16,16]
        float* __restrict__ agg,          // [N,16] zeroed
        int E) {
    // Wl[k][o][i] padded: row stride 20 floats (80B), k stride 320 floats.
    __shared__ float Wl[25 * 320];
    for (int idx = threadIdx.x; idx < 25 * 256; idx += blockDim.x) {
        int k = idx >> 8;
        int r = idx & 255;
        int i = r >> 4;
        int o = r & 15;
        Wl[k * 320 + o * 20 + i] = W[idx];
    }
    __syncthreads();

    int gs = gridDim.x * blockDim.x;
    int total = E * 16;
    for (int t = blockIdx.x * blockDim.x + threadIdx.x; t < total; t += gs) {
        int e = t >> 4;
        int o = t & 15;
        int s;
        float b[4];
        int wi[4];
        decode_or_compute(HASPACK, pack, eattr, srcp, e, s, b, wi);

        const float4* h4 = reinterpret_cast<const float4*>(h + (size_t)s * 16);
        float4 h0 = h4[0], h1 = h4[1], h2 = h4[2], h3 = h4[3];

        float acc = 0.0f;
        #pragma unroll
        for (int sp = 0; sp < 4; ++sp) {
            const float* wp = &Wl[wi[sp] * 320 + o * 20];
            float4 w0 = *reinterpret_cast<const float4*>(wp);
            float4 w1 = *reinterpret_cast<const float4*>(wp + 4);
            float4 w2 = *reinterpret_cast<const float4*>(wp + 8);
            float4 w3 = *reinterpret_cast<const float4*>(wp + 12);
            float p = h0.x * w0.x + h0.y * w0.y + h0.z * w0.z + h0.w * w0.w
                    + h1.x * w1.x + h1.y * w1.y + h1.z * w1.z + h1.w * w1.w
                    + h2.x * w2.x + h2.y * w2.y + h2.z * w2.z + h2.w * w2.w
                    + h3.x * w3.x + h3.y * w3.y + h3.z * w3.z + h3.w * w3.w;
            acc += b[sp] * p;
        }
        atomicAdd(&agg[(size_t)dst[e] * 16 + o], acc);
    }
}

template <bool HASPACK>
__global__ __launch_bounds__(256) void edge2_kernel(
        const float* __restrict__ x,      // [N,2]
        const int* __restrict__ dst,
        const uint4* __restrict__ pack,
        const float* __restrict__ eattr,
        const int* __restrict__ srcp,
        const float* __restrict__ W,      // [25,2,16]
        float* __restrict__ agg,          // [N,16] zeroed
        int E) {
    // Wl[k][o][i] row stride 6 floats (24B, 8B-aligned), k stride 96 floats.
    __shared__ float Wl[25 * 96];
    for (int idx = threadIdx.x; idx < 25 * 32; idx += blockDim.x) {
        int k = idx >> 5;
        int r = idx & 31;
        int i = r >> 4;
        int o = r & 15;
        Wl[k * 96 + o * 6 + i] = W[idx];
    }
    __syncthreads();

    int gs = gridDim.x * blockDim.x;
    int total = E * 16;
    for (int t = blockIdx.x * blockDim.x + threadIdx.x; t < total; t += gs) {
        int e = t >> 4;
        int o = t & 15;
        int s;
        float b[4];
        int wi[4];
        decode_or_compute(HASPACK, pack, eattr, srcp, e, s, b, wi);

        float2 xv = reinterpret_cast<const float2*>(x)[s];

        float acc = 0.0f;
        #pragma unroll
        for (int sp = 0; sp < 4; ++sp) {
            float2 w = *reinterpret_cast<const float2*>(&Wl[wi[sp] * 96 + o * 6]);
            acc += b[sp] * (xv.x * w.x + xv.y * w.y);
        }
        atomicAdd(&agg[(size_t)dst[e] * 16 + o], acc);
    }
}

// ---- finalize: out = relu(agg * invdeg + hin @ root + bias) ----------------
template <int IN>
__global__ void finalize_kernel(const float* __restrict__ hin,    // [N, IN]
                                const float* __restrict__ root,   // [IN, 16]
                                const float* __restrict__ bias,   // [16]
                                const float* __restrict__ invdeg, // [N]
                                float* __restrict__ h,            // [N,16] in: agg / out: act
                                int N) {
    int t = blockIdx.x * blockDim.x + threadIdx.x;
    if (t >= N * 16) return;
    int o = t & 15;
    int n = t >> 4;
    float acc = h[t] * invdeg[n];
    #pragma unroll
    for (int i = 0; i < IN; ++i) acc += hin[(size_t)n * IN + i] * root[i * 16 + o];
    acc += bias[o];
    h[t] = fmaxf(acc, 0.0f);
}

// ---- final FC + sigmoid ----------------------------------------------------
__global__ void fc_kernel(const float* __restrict__ h,   // [N,16]
                          const float* __restrict__ fcw, // [16]
                          const float* __restrict__ fcb, // [1]
                          float* __restrict__ out, int N) {
    int n = blockIdx.x * blockDim.x + threadIdx.x;
    if (n >= N) return;
    const float4* h4 = reinterpret_cast<const float4*>(h + (size_t)n * 16);
    float acc = fcb[0];
    #pragma unroll
    for (int q = 0; q < 4; ++q) {
        float4 v = h4[q];
        acc += v.x * fcw[4 * q + 0] + v.y * fcw[4 * q + 1] +
               v.z * fcw[4 * q + 2] + v.w * fcw[4 * q + 3];
    }
    out[n] = 1.0f / (1.0f + expf(-acc));
}

extern "C" void kernel_launch(void* const* d_in, const int* in_sizes, int n_in,
                              void* d_out, int out_size, void* d_ws, size_t ws_size,
                              hipStream_t stream) {
    const float* x      = (const float*)d_in[0];   // [N,2]
    const int*   eidx   = (const int*)d_in[1];     // [2,E]
    const float* eattr  = (const float*)d_in[2];   // [E,2]
    const float* W1     = (const float*)d_in[3];
    const float* root1  = (const float*)d_in[4];
    const float* b1     = (const float*)d_in[5];
    const float* W2     = (const float*)d_in[6];
    const float* root2  = (const float*)d_in[7];
    const float* b2     = (const float*)d_in[8];
    const float* W3     = (const float*)d_in[9];
    const float* root3  = (const float*)d_in[10];
    const float* b3     = (const float*)d_in[11];
    const float* fcw    = (const float*)d_in[12];
    const float* fcb    = (const float*)d_in[13];
    float* out = (float*)d_out;

    const int N = in_sizes[0] / 2;
    const int E = in_sizes[2] / 2;
    const int* src = eidx;
    const int* dst = eidx + E;

    float* hA  = (float*)d_ws;            // [N,16]
    float* hB  = hA + (size_t)N * 16;     // [N,16]
    float* deg = hB + (size_t)N * 16;     // [N]
    // pack buffer after deg, 16B aligned
    size_t base = (size_t)N * 33;
    base = (base + 3) & ~(size_t)3;       // align to 16B in floats
    uint4* pack = (uint4*)((float*)d_ws + base);
    size_t need = (base + (size_t)E * 4) * sizeof(float);
    bool haspack = ws_size >= need;

    const int BT = 256;
    const int EG = 2048;                   // grid-stride blocks for edge kernels
    const int node_grid = (N * 16 + BT - 1) / BT;

    // degree + basis pack (shared by all layers)
    hipMemsetAsync(deg, 0, (size_t)N * sizeof(float), stream);
    deg_count_kernel<<<2048, BT, 0, stream>>>(dst, deg, E);
    deg_inv_kernel<<<(N + BT - 1) / BT, BT, 0, stream>>>(deg, N);
    if (haspack)
        pack_kernel<<<2048, BT, 0, stream>>>(eattr, src, pack, E);

    // layer 1: x[N,2] -> hA
    hipMemsetAsync(hA, 0, (size_t)N * 16 * sizeof(float), stream);
    if (haspack)
        edge2_kernel<true><<<EG, BT, 0, stream>>>(x, dst, pack, eattr, src, W1, hA, E);
    else
        edge2_kernel<false><<<EG, BT, 0, stream>>>(x, dst, pack, eattr, src, W1, hA, E);
    finalize_kernel<2><<<node_grid, BT, 0, stream>>>(x, root1, b1, deg, hA, N);

    // layer 2: hA -> hB
    hipMemsetAsync(hB, 0, (size_t)N * 16 * sizeof(float), stream);
    if (haspack)
        edge16_kernel<true><<<EG, BT, 0, stream>>>(hA, dst, pack, eattr, src, W2, hB, E);
    else
        edge16_kernel<false><<<EG, BT, 0, stream>>>(hA, dst, pack, eattr, src, W2, hB, E);
    finalize_kernel<16><<<node_grid, BT, 0, stream>>>(hA, root2, b2, deg, hB, N);

    // layer 3: hB -> hA
    hipMemsetAsync(hA, 0, (size_t)N * 16 * sizeof(float), stream);
    if (haspack)
        edge16_kernel<true><<<EG, BT, 0, stream>>>(hB, dst, pack, eattr, src, W3, hA, E);
    else
        edge16_kernel<false><<<EG, BT, 0, stream>>>(hB, dst, pack, eattr, src, W3, hA, E);
    finalize_kernel<16><<<node_grid, BT, 0, stream>>>(hB, root3, b3, deg, hA, N);

    // final FC + sigmoid
    fc_kernel<<<(N + BT - 1) / BT, BT, 0, stream>>>(hA, fcw, fcb, out, N);
}